// Round 2
// baseline (251.198 us; speedup 1.0000x reference)
//
#include <hip/hip_runtime.h>
#include <hip/hip_fp16.h>

// Problem constants (B=4, C=128, H=W=64 -> HW=4096)
#define BATCH 4
#define CCH   128
#define HWSZ  4096

typedef _Float16 half8 __attribute__((ext_vector_type(8)));
typedef short short8 __attribute__((ext_vector_type(8)));
typedef float floatx4 __attribute__((ext_vector_type(4)));
typedef unsigned short ushort4v __attribute__((ext_vector_type(4)));

__device__ __forceinline__ unsigned short f2bf(float f) {
    union { float f; unsigned u; } v; v.f = f;
    unsigned r = (v.u + 0x7fffu + ((v.u >> 16) & 1u)) >> 16;
    return (unsigned short)r;
}

// prep: x fp32 [B][C][HW] -> xt fp16 [B][HW][C] (transposed), xf bf16 [B][C][HW]
__global__ __launch_bounds__(256) void prep_kernel(
    const float* __restrict__ x1, const float* __restrict__ x2,
    _Float16* __restrict__ x1t, _Float16* __restrict__ x2t,
    unsigned short* __restrict__ x1f, unsigned short* __restrict__ x2f)
{
    __shared__ float lds[32][33];
    int idx = blockIdx.x;            // 0..4095
    int which = idx >> 11;           // 0: x1, 1: x2
    int r = idx & 2047;
    int cb  = r & 3;                 // C/32  = 4
    int hwb = (r >> 2) & 127;        // HW/32 = 128
    int b   = r >> 9;                // 4 batches
    const float* x = which ? x2 : x1;
    _Float16* xt = which ? x2t : x1t;
    unsigned short* xf = which ? x2f : x1f;
    int tid = threadIdx.x;
    int tc = tid >> 5, th = tid & 31;
    #pragma unroll
    for (int k = 0; k < 4; ++k) {
        int cl = tc + 8 * k;
        int c = cb * 32 + cl, hw = hwb * 32 + th;
        float v = x[((size_t)b * CCH + c) * HWSZ + hw];
        lds[cl][th] = v;
        xf[((size_t)b * CCH + c) * HWSZ + hw] = f2bf(v);
    }
    __syncthreads();
    #pragma unroll
    for (int k = 0; k < 4; ++k) {
        int hl = tc + 8 * k;
        xt[((size_t)b * HWSZ + hwb * 32 + hl) * CCH + cb * 32 + th] =
            (_Float16)lds[th][hl];
    }
}

// Fused partial pass: for col-slice `slice` (64 cols) and loop-part `part`
// (4096/P rows), compute partial accP[c=128][col=64] and colsum[64]:
//   A[row,col] = sum_c loopT[row][c]*blockT[col][c]   (fp16 MFMA, K=128)
//   E = exp(A) (bf16 -> swizzled LDS, double-buffered)
//   accP[c][col] += sum_row loopF[c][row]*E[row][col] (bf16 MFMA)
//   colsum[col]  += sum_row E
__global__ __launch_bounds__(512, 4) void fused_part(
    const _Float16* __restrict__ loopT,
    const _Float16* __restrict__ blockT,
    const unsigned short* __restrict__ loopF,
    float* __restrict__ accPo,    // [P][B][64][128][64]
    float* __restrict__ cso,      // [P][B][64][64]
    int P)
{
    __shared__ unsigned short ldsE[2][64 * 64];  // bank-aligned, XOR-swizzled
    __shared__ float cspart[4][64];

    int bid = blockIdx.x;
    int xcd = bid & 7, grp = bid >> 3;      // grp in 0..32P-1
    int b    = xcd >> 1;                    // 2 XCDs per batch (L2 locality)
    int part = grp >> 5;
    int slice = (grp & 31) + 32 * (xcd & 1);
    int tid = threadIdx.x;
    int wave = tid >> 6, lane = tid & 63;
    int l16 = lane & 15, lg = lane >> 4;
    int nt = wave & 3, mh = wave >> 2;
    int NC = 64 / P;
    int ch0 = part * NC, ch1 = ch0 + NC;

    const _Float16* lT = loopT + (size_t)b * HWSZ * CCH;
    const _Float16* bT = blockT + (size_t)b * HWSZ * CCH;
    const unsigned short* lF = loopF + (size_t)b * CCH * HWSZ;

    // hoist gram B-operand (block-side cols slice*64 + mh*32 + t*16 + l16, K=128)
    half8 bfrag[2][4];
    #pragma unroll
    for (int t = 0; t < 2; ++t)
        #pragma unroll
        for (int ks = 0; ks < 4; ++ks)
            bfrag[t][ks] = *(const half8*)&bT[
                (size_t)(slice * 64 + mh * 32 + t * 16 + l16) * CCH + ks * 32 + lg * 8];

    const _Float16* aBase = lT + (size_t)(nt * 16 + l16) * CCH + lg * 8;
    const unsigned short* fBase = lF + (size_t)(wave * 16 + l16) * HWSZ + lg * 8;

    // swizzled LDS offsets (ushort units): phys = col*64 + ((row>>3)^(col&7))*8 + (row&7)
    int swz = l16 & 7;
    int wo0 = (mh * 32 + l16) * 64 + (((2 * nt + (lg >> 1)) ^ swz) << 3) + ((lg & 1) << 2);
    int wo1 = wo0 + 16 * 64;                       // e1 cols are +16
    int ur0 = (lg ^ swz) << 3;                     // rows 8lg..+7   (k-half 0)
    int ur1 = ((4 + lg) ^ swz) << 3;               // rows 32+8lg..  (k-half 1)

    float csum0 = 0.f, csum1 = 0.f;
    floatx4 accP[4];
    #pragma unroll
    for (int mt = 0; mt < 4; ++mt) accP[mt] = (floatx4){0.f, 0.f, 0.f, 0.f};

    // prologue: load gram A-frags for first chunk
    half8 af[4];
    #pragma unroll
    for (int ks = 0; ks < 4; ++ks)
        af[ks] = *(const half8*)(aBase + (size_t)ch0 * 64 * CCH + ks * 32);

    for (int ch = ch0; ch < ch1; ++ch) {
        // ---- gram: A-chunk [64 rows x 64 cols], K=128 (fp16 MFMA)
        floatx4 accA0 = {0.f, 0.f, 0.f, 0.f}, accA1 = {0.f, 0.f, 0.f, 0.f};
        #pragma unroll
        for (int ks = 0; ks < 4; ++ks) {
            accA0 = __builtin_amdgcn_mfma_f32_16x16x32_f16(af[ks], bfrag[0][ks], accA0, 0, 0, 0);
            accA1 = __builtin_amdgcn_mfma_f32_16x16x32_f16(af[ks], bfrag[1][ks], accA1, 0, 0, 0);
        }
        // ---- prefetch next chunk's A-frags (hidden under exp + barrier + PV)
        int chn = (ch + 1 < ch1) ? ch + 1 : ch;
        half8 afn[4];
        #pragma unroll
        for (int ks = 0; ks < 4; ++ks)
            afn[ks] = *(const half8*)(aBase + (size_t)chn * 64 * CCH + ks * 32);
        // ---- exp (no max-subtraction: |A| << 88) + bf16 pack
        ushort4v e0, e1;
        #pragma unroll
        for (int rr = 0; rr < 4; ++rr) {
            float v0 = __expf(accA0[rr]); csum0 += v0; e0[rr] = f2bf(v0);
            float v1 = __expf(accA1[rr]); csum1 += v1; e1[rr] = f2bf(v1);
        }
        // D-frag rows nt*16+lg*4+rr at cols mh*32+{0,16}+l16 -> swizzled store
        unsigned short* eb = ldsE[ch & 1];
        *(ushort4v*)&eb[wo0] = e0;
        *(ushort4v*)&eb[wo1] = e1;
        // ---- PV A-frags for CURRENT chunk (latency hides under barrier)
        const unsigned short* fp = fBase + ch * 64;
        short8 pa0 = *(const short8*)fp;
        short8 pa1 = *(const short8*)(fp + 32);
        __syncthreads();   // E tile visible (single barrier; double-buffered)
        // ---- PV: accP[c-tile=wave][4 col-tiles], k = 64 rows (bf16 MFMA)
        const unsigned short* ebr = ldsE[ch & 1];
        #pragma unroll
        for (int mt = 0; mt < 4; ++mt) {
            int cb = (mt * 16 + l16) * 64;
            short8 pb0 = *(const short8*)&ebr[cb + ur0];
            short8 pb1 = *(const short8*)&ebr[cb + ur1];
            accP[mt] = __builtin_amdgcn_mfma_f32_16x16x32_bf16(pa0, pb0, accP[mt], 0, 0, 0);
            accP[mt] = __builtin_amdgcn_mfma_f32_16x16x32_bf16(pa1, pb1, accP[mt], 0, 0, 0);
        }
        #pragma unroll
        for (int ks = 0; ks < 4; ++ks) af[ks] = afn[ks];
    }

    // ---- colsum: deterministic cross-wave reduce
    float v = csum0;
    v += __shfl_xor(v, 16, 64); v += __shfl_xor(v, 32, 64);
    float w = csum1;
    w += __shfl_xor(w, 16, 64); w += __shfl_xor(w, 32, 64);
    if (lane < 16) {
        cspart[nt][mh * 32 + lane] = v;
        cspart[nt][mh * 32 + 16 + lane] = w;
    }
    __syncthreads();
    size_t sbase = ((size_t)part * BATCH + b) * 64 + slice;
    if (tid < 64)
        cso[sbase * 64 + tid] =
            cspart[0][tid] + cspart[1][tid] + cspart[2][tid] + cspart[3][tid];

    // ---- store partial accP: c = wave*16 + lg*4 + rr, col = mt*16 + l16
    float* po = accPo + sbase * 128 * 64;
    #pragma unroll
    for (int mt = 0; mt < 4; ++mt)
        #pragma unroll
        for (int rr = 0; rr < 4; ++rr)
            po[(size_t)(wave * 16 + lg * 4 + rr) * 64 + mt * 16 + l16] = accP[mt][rr];
}

// combine partials + epilogue: att = (sum_p accP)/(sum_p colsum);
// out[col] (+)= cw * sum_c gw[c]*sigmoid(att[c][col])*xe[c][col]
template<int ACCUM>
__global__ __launch_bounds__(256) void combine_kernel(
    const float* __restrict__ accPp, const float* __restrict__ csp,
    const float* __restrict__ xe, const float* __restrict__ gw,
    const float* __restrict__ cwp, float* __restrict__ out, int P)
{
    __shared__ float red[256];
    __shared__ float gws[CCH];
    int bid = blockIdx.x;            // 256: b = bid>>6, slice = bid&63
    int b = bid >> 6, slice = bid & 63;
    int tid = threadIdx.x;
    if (tid < CCH) gws[tid] = gw[tid];
    __syncthreads();
    int col = tid & 63, cq = tid >> 6;
    float cs = 0.f;
    for (int p = 0; p < P; ++p)
        cs += csp[(((size_t)p * BATCH + b) * 64 + slice) * 64 + col];
    float inv = 1.f / cs;
    float acc = 0.f;
    for (int ci = 0; ci < 32; ++ci) {
        int c = cq * 32 + ci;
        float s = 0.f;
        for (int p = 0; p < P; ++p)
            s += accPp[((((size_t)p * BATCH + b) * 64 + slice) * 128 + c) * 64 + col];
        float att = s * inv;
        float mask = 1.f / (1.f + __expf(-att));
        acc += gws[c] * mask * xe[((size_t)b * CCH + c) * HWSZ + slice * 64 + col];
    }
    red[tid] = acc;
    __syncthreads();
    if (tid < 64) {
        float tot = red[tid] + red[tid + 64] + red[tid + 128] + red[tid + 192];
        float vv = cwp[0] * tot;
        size_t o = (size_t)b * HWSZ + slice * 64 + tid;
        if (ACCUM) out[o] += vv; else out[o] = vv;
    }
}

extern "C" void kernel_launch(void* const* d_in, const int* in_sizes, int n_in,
                              void* d_out, int out_size, void* d_ws, size_t ws_size,
                              hipStream_t stream) {
    const float* x1 = (const float*)d_in[0];
    const float* x2 = (const float*)d_in[1];
    const float* gw = (const float*)d_in[2];
    const float* cw = (const float*)d_in[3];
    float* out = (float*)d_out;

    char* ws = (char*)d_ws;
    size_t elems = (size_t)BATCH * CCH * HWSZ;  // 2M
    _Float16* x1t = (_Float16*)ws;
    _Float16* x2t = (_Float16*)(ws + elems * 2);
    unsigned short* x1f = (unsigned short*)(ws + elems * 4);
    unsigned short* x2f = (unsigned short*)(ws + elems * 6);
    char* pbase = ws + elems * 8;               // 16 MB used by prep arrays

    // partial region sizing (per pass): accP P*8MB + colsum P*64KB
    auto region = [](int P) {
        return (size_t)P * BATCH * 64 * 128 * 64 * 4 + (size_t)P * BATCH * 64 * 64 * 4;
    };
    size_t avail = (ws_size > elems * 8) ? ws_size - elems * 8 : 0;
    int P; bool dual;
    if (avail >= 2 * region(2))      { P = 2; dual = true;  }
    else if (avail >= region(2))     { P = 2; dual = false; }
    else                             { P = 1; dual = false; }

    size_t accPbytes = (size_t)P * BATCH * 64 * 128 * 64 * 4;
    float* accP1 = (float*)pbase;
    float* cs1   = (float*)(pbase + accPbytes);
    float* accP2 = dual ? (float*)(pbase + region(P)) : accP1;
    float* cs2   = dual ? (float*)(pbase + region(P) + accPbytes) : cs1;

    prep_kernel<<<4096, 256, 0, stream>>>(x1, x2, x1t, x2t, x1f, x2f);

    if (dual) {
        // pass1 (out2 over m): loopT=x1t, blockT=x2t, loopF=x1f, xe=x2
        fused_part<<<256 * P, 512, 0, stream>>>(x1t, x2t, x1f, accP1, cs1, P);
        // pass2 (out1 over n): loopT=x2t, blockT=x1t, loopF=x2f, xe=x1
        fused_part<<<256 * P, 512, 0, stream>>>(x2t, x1t, x2f, accP2, cs2, P);
        combine_kernel<0><<<256, 256, 0, stream>>>(accP1, cs1, x2, gw, cw, out, P);
        combine_kernel<1><<<256, 256, 0, stream>>>(accP2, cs2, x1, gw, cw, out, P);
    } else {
        fused_part<<<256 * P, 512, 0, stream>>>(x1t, x2t, x1f, accP1, cs1, P);
        combine_kernel<0><<<256, 256, 0, stream>>>(accP1, cs1, x2, gw, cw, out, P);
        fused_part<<<256 * P, 512, 0, stream>>>(x2t, x1t, x2f, accP1, cs1, P);
        combine_kernel<1><<<256, 256, 0, stream>>>(accP1, cs1, x1, gw, cw, out, P);
    }
}

// Round 3
// 250.508 us; speedup vs baseline: 1.0028x; 1.0028x over previous
//
#include <hip/hip_runtime.h>
#include <hip/hip_fp16.h>

// Problem constants (B=4, C=128, H=W=64 -> HW=4096)
#define BATCH 4
#define CCH   128
#define HWSZ  4096

typedef _Float16 half8 __attribute__((ext_vector_type(8)));
typedef short short8 __attribute__((ext_vector_type(8)));
typedef float floatx4 __attribute__((ext_vector_type(4)));
typedef unsigned short ushort4v __attribute__((ext_vector_type(4)));

__device__ __forceinline__ unsigned short f2bf(float f) {
    union { float f; unsigned u; } v; v.f = f;
    unsigned r = (v.u + 0x7fffu + ((v.u >> 16) & 1u)) >> 16;
    return (unsigned short)r;
}

// prep: x fp32 [B][C][HW] -> xt fp16 [B][HW][C] (transposed), xf bf16 [B][C][HW]
__global__ __launch_bounds__(256) void prep_kernel(
    const float* __restrict__ x1, const float* __restrict__ x2,
    _Float16* __restrict__ x1t, _Float16* __restrict__ x2t,
    unsigned short* __restrict__ x1f, unsigned short* __restrict__ x2f)
{
    __shared__ float lds[32][33];
    int idx = blockIdx.x;            // 0..4095
    int which = idx >> 11;           // 0: x1, 1: x2
    int r = idx & 2047;
    int cb  = r & 3;                 // C/32  = 4
    int hwb = (r >> 2) & 127;        // HW/32 = 128
    int b   = r >> 9;                // 4 batches
    const float* x = which ? x2 : x1;
    _Float16* xt = which ? x2t : x1t;
    unsigned short* xf = which ? x2f : x1f;
    int tid = threadIdx.x;
    int tc = tid >> 5, th = tid & 31;
    #pragma unroll
    for (int k = 0; k < 4; ++k) {
        int cl = tc + 8 * k;
        int c = cb * 32 + cl, hw = hwb * 32 + th;
        float v = x[((size_t)b * CCH + c) * HWSZ + hw];
        lds[cl][th] = v;
        xf[((size_t)b * CCH + c) * HWSZ + hw] = f2bf(v);
    }
    __syncthreads();
    #pragma unroll
    for (int k = 0; k < 4; ++k) {
        int hl = tc + 8 * k;
        xt[((size_t)b * HWSZ + hwb * 32 + hl) * CCH + cb * 32 + th] =
            (_Float16)lds[th][hl];
    }
}

// Fused partial pass: for col-slice `slice` (64 cols) and loop-part `part`
// (4096/P rows), compute partial accP[c=128][col=64] and colsum[64]:
//   A[row,col] = sum_c loopT[row][c]*blockT[col][c]   (fp16 MFMA, K=128)
//   E = exp(A) (bf16 -> swizzled LDS, double-buffered)
//   accP[c][col] += sum_row loopF[c][row]*E[row][col] (bf16 MFMA)
//   colsum[col]  += sum_row E
// Per-chunk sync is a RAW s_barrier + lgkmcnt(0) only (no vmcnt drain):
// global prefetches stay in flight across the barrier (T4). Safe with the
// double-buffered E tile: a wave's ds_reads of buf[i&1] are complete
// (its own lgkmcnt(0)) before it passes barrier i+1, and buf[i&1] is only
// rewritten after barrier i+1.
__global__ __launch_bounds__(512, 4) void fused_part(
    const _Float16* __restrict__ loopT,
    const _Float16* __restrict__ blockT,
    const unsigned short* __restrict__ loopF,
    float* __restrict__ accPo,    // [P][B][64][128][64]
    float* __restrict__ cso,      // [P][B][64][64]
    int P)
{
    __shared__ unsigned short ldsE[2][64 * 64];  // bank-aligned, XOR-swizzled
    __shared__ float cspart[4][64];

    int bid = blockIdx.x;
    int xcd = bid & 7, grp = bid >> 3;      // grp in 0..32P-1
    int b    = xcd >> 1;                    // 2 XCDs per batch (L2 locality)
    int part = grp >> 5;
    int slice = (grp & 31) + 32 * (xcd & 1);
    int tid = threadIdx.x;
    int wave = tid >> 6, lane = tid & 63;
    int l16 = lane & 15, lg = lane >> 4;
    int nt = wave & 3, mh = wave >> 2;
    int NC = 64 / P;
    int ch0 = part * NC, ch1 = ch0 + NC;

    const _Float16* lT = loopT + (size_t)b * HWSZ * CCH;
    const _Float16* bT = blockT + (size_t)b * HWSZ * CCH;
    const unsigned short* lF = loopF + (size_t)b * CCH * HWSZ;

    // hoist gram B-operand (block-side cols slice*64 + mh*32 + t*16 + l16, K=128)
    half8 bfrag[2][4];
    #pragma unroll
    for (int t = 0; t < 2; ++t)
        #pragma unroll
        for (int ks = 0; ks < 4; ++ks)
            bfrag[t][ks] = *(const half8*)&bT[
                (size_t)(slice * 64 + mh * 32 + t * 16 + l16) * CCH + ks * 32 + lg * 8];

    const _Float16* aBase = lT + (size_t)(nt * 16 + l16) * CCH + lg * 8;
    const unsigned short* fBase = lF + (size_t)(wave * 16 + l16) * HWSZ + lg * 8;

    // swizzled LDS offsets (ushort units): phys = col*64 + ((row>>3)^(col&7))*8 + (row&7)
    int swz = l16 & 7;
    int wo0 = (mh * 32 + l16) * 64 + (((2 * nt + (lg >> 1)) ^ swz) << 3) + ((lg & 1) << 2);
    int wo1 = wo0 + 16 * 64;                       // e1 cols are +16
    int ur0 = (lg ^ swz) << 3;                     // rows 8lg..+7   (k-half 0)
    int ur1 = ((4 + lg) ^ swz) << 3;               // rows 32+8lg..  (k-half 1)

    float csum0 = 0.f, csum1 = 0.f;
    floatx4 accP[4];
    #pragma unroll
    for (int mt = 0; mt < 4; ++mt) accP[mt] = (floatx4){0.f, 0.f, 0.f, 0.f};

    // prologue: load gram A-frags for first chunk
    half8 af[4];
    #pragma unroll
    for (int ks = 0; ks < 4; ++ks)
        af[ks] = *(const half8*)(aBase + (size_t)ch0 * 64 * CCH + ks * 32);

    for (int ch = ch0; ch < ch1; ++ch) {
        // ---- issue PV A-frags (current chunk) + gram A-frags (next chunk):
        // both ride across the barrier with NO vmcnt drain, latency hidden
        // under gram MFMA + exp.
        const unsigned short* fp = fBase + ch * 64;
        short8 pa0 = *(const short8*)fp;
        short8 pa1 = *(const short8*)(fp + 32);
        int chn = (ch + 1 < ch1) ? ch + 1 : ch;
        half8 afn[4];
        #pragma unroll
        for (int ks = 0; ks < 4; ++ks)
            afn[ks] = *(const half8*)(aBase + (size_t)chn * 64 * CCH + ks * 32);
        // ---- gram: A-chunk [64 rows x 64 cols], K=128 (fp16 MFMA)
        floatx4 accA0 = {0.f, 0.f, 0.f, 0.f}, accA1 = {0.f, 0.f, 0.f, 0.f};
        #pragma unroll
        for (int ks = 0; ks < 4; ++ks) {
            accA0 = __builtin_amdgcn_mfma_f32_16x16x32_f16(af[ks], bfrag[0][ks], accA0, 0, 0, 0);
            accA1 = __builtin_amdgcn_mfma_f32_16x16x32_f16(af[ks], bfrag[1][ks], accA1, 0, 0, 0);
        }
        // ---- exp (no max-subtraction: |A| << 88) + bf16 pack
        ushort4v e0, e1;
        #pragma unroll
        for (int rr = 0; rr < 4; ++rr) {
            float v0 = __expf(accA0[rr]); csum0 += v0; e0[rr] = f2bf(v0);
            float v1 = __expf(accA1[rr]); csum1 += v1; e1[rr] = f2bf(v1);
        }
        // D-frag rows nt*16+lg*4+rr at cols mh*32+{0,16}+l16 -> swizzled store
        unsigned short* eb = ldsE[ch & 1];
        *(ushort4v*)&eb[wo0] = e0;
        *(ushort4v*)&eb[wo1] = e1;
        // ---- raw barrier: LDS-write drain only; globals stay in flight
        __builtin_amdgcn_sched_barrier(0);
        asm volatile("s_waitcnt lgkmcnt(0)");
        __builtin_amdgcn_s_barrier();
        __builtin_amdgcn_sched_barrier(0);
        // ---- PV: accP[c-tile=wave][4 col-tiles], k = 64 rows (bf16 MFMA)
        const unsigned short* ebr = ldsE[ch & 1];
        #pragma unroll
        for (int mt = 0; mt < 4; ++mt) {
            int cb = (mt * 16 + l16) * 64;
            short8 pb0 = *(const short8*)&ebr[cb + ur0];
            short8 pb1 = *(const short8*)&ebr[cb + ur1];
            accP[mt] = __builtin_amdgcn_mfma_f32_16x16x32_bf16(pa0, pb0, accP[mt], 0, 0, 0);
            accP[mt] = __builtin_amdgcn_mfma_f32_16x16x32_bf16(pa1, pb1, accP[mt], 0, 0, 0);
        }
        #pragma unroll
        for (int ks = 0; ks < 4; ++ks) af[ks] = afn[ks];
    }

    // ---- colsum: deterministic cross-wave reduce
    float v = csum0;
    v += __shfl_xor(v, 16, 64); v += __shfl_xor(v, 32, 64);
    float w = csum1;
    w += __shfl_xor(w, 16, 64); w += __shfl_xor(w, 32, 64);
    if (lane < 16) {
        cspart[nt][mh * 32 + lane] = v;
        cspart[nt][mh * 32 + 16 + lane] = w;
    }
    __syncthreads();
    size_t sbase = ((size_t)part * BATCH + b) * 64 + slice;
    if (tid < 64)
        cso[sbase * 64 + tid] =
            cspart[0][tid] + cspart[1][tid] + cspart[2][tid] + cspart[3][tid];

    // ---- store partial accP: c = wave*16 + lg*4 + rr, col = mt*16 + l16
    float* po = accPo + sbase * 128 * 64;
    #pragma unroll
    for (int mt = 0; mt < 4; ++mt)
        #pragma unroll
        for (int rr = 0; rr < 4; ++rr)
            po[(size_t)(wave * 16 + lg * 4 + rr) * 64 + mt * 16 + l16] = accP[mt][rr];
}

// combine partials + epilogue: att = (sum_p accP)/(sum_p colsum);
// out[col] (+)= cw * sum_c gw[c]*sigmoid(att[c][col])*xe[c][col]
template<int ACCUM>
__global__ __launch_bounds__(256) void combine_kernel(
    const float* __restrict__ accPp, const float* __restrict__ csp,
    const float* __restrict__ xe, const float* __restrict__ gw,
    const float* __restrict__ cwp, float* __restrict__ out, int P)
{
    __shared__ float red[256];
    __shared__ float gws[CCH];
    int bid = blockIdx.x;            // 256: b = bid>>6, slice = bid&63
    int b = bid >> 6, slice = bid & 63;
    int tid = threadIdx.x;
    if (tid < CCH) gws[tid] = gw[tid];
    __syncthreads();
    int col = tid & 63, cq = tid >> 6;
    float cs = 0.f;
    for (int p = 0; p < P; ++p)
        cs += csp[(((size_t)p * BATCH + b) * 64 + slice) * 64 + col];
    float inv = 1.f / cs;
    float acc = 0.f;
    for (int ci = 0; ci < 32; ++ci) {
        int c = cq * 32 + ci;
        float s = 0.f;
        for (int p = 0; p < P; ++p)
            s += accPp[((((size_t)p * BATCH + b) * 64 + slice) * 128 + c) * 64 + col];
        float att = s * inv;
        float mask = 1.f / (1.f + __expf(-att));
        acc += gws[c] * mask * xe[((size_t)b * CCH + c) * HWSZ + slice * 64 + col];
    }
    red[tid] = acc;
    __syncthreads();
    if (tid < 64) {
        float tot = red[tid] + red[tid + 64] + red[tid + 128] + red[tid + 192];
        float vv = cwp[0] * tot;
        size_t o = (size_t)b * HWSZ + slice * 64 + tid;
        if (ACCUM) out[o] += vv; else out[o] = vv;
    }
}

extern "C" void kernel_launch(void* const* d_in, const int* in_sizes, int n_in,
                              void* d_out, int out_size, void* d_ws, size_t ws_size,
                              hipStream_t stream) {
    const float* x1 = (const float*)d_in[0];
    const float* x2 = (const float*)d_in[1];
    const float* gw = (const float*)d_in[2];
    const float* cw = (const float*)d_in[3];
    float* out = (float*)d_out;

    char* ws = (char*)d_ws;
    size_t elems = (size_t)BATCH * CCH * HWSZ;  // 2M
    _Float16* x1t = (_Float16*)ws;
    _Float16* x2t = (_Float16*)(ws + elems * 2);
    unsigned short* x1f = (unsigned short*)(ws + elems * 4);
    unsigned short* x2f = (unsigned short*)(ws + elems * 6);
    char* pbase = ws + elems * 8;               // 16 MB used by prep arrays

    // partial region sizing (per pass): accP P*8MB + colsum P*64KB
    auto region = [](int P) {
        return (size_t)P * BATCH * 64 * 128 * 64 * 4 + (size_t)P * BATCH * 64 * 64 * 4;
    };
    size_t avail = (ws_size > elems * 8) ? ws_size - elems * 8 : 0;
    int P; bool dual;
    if (avail >= 2 * region(2))      { P = 2; dual = true;  }
    else if (avail >= region(2))     { P = 2; dual = false; }
    else                             { P = 1; dual = false; }

    size_t accPbytes = (size_t)P * BATCH * 64 * 128 * 64 * 4;
    float* accP1 = (float*)pbase;
    float* cs1   = (float*)(pbase + accPbytes);
    float* accP2 = dual ? (float*)(pbase + region(P)) : accP1;
    float* cs2   = dual ? (float*)(pbase + region(P) + accPbytes) : cs1;

    prep_kernel<<<4096, 256, 0, stream>>>(x1, x2, x1t, x2t, x1f, x2f);

    if (dual) {
        // pass1 (out2 over m): loopT=x1t, blockT=x2t, loopF=x1f, xe=x2
        fused_part<<<256 * P, 512, 0, stream>>>(x1t, x2t, x1f, accP1, cs1, P);
        // pass2 (out1 over n): loopT=x2t, blockT=x1t, loopF=x2f, xe=x1
        fused_part<<<256 * P, 512, 0, stream>>>(x2t, x1t, x2f, accP2, cs2, P);
        combine_kernel<0><<<256, 256, 0, stream>>>(accP1, cs1, x2, gw, cw, out, P);
        combine_kernel<1><<<256, 256, 0, stream>>>(accP2, cs2, x1, gw, cw, out, P);
    } else {
        fused_part<<<256 * P, 512, 0, stream>>>(x1t, x2t, x1f, accP1, cs1, P);
        combine_kernel<0><<<256, 256, 0, stream>>>(accP1, cs1, x2, gw, cw, out, P);
        fused_part<<<256 * P, 512, 0, stream>>>(x2t, x1t, x2f, accP1, cs1, P);
        combine_kernel<1><<<256, 256, 0, stream>>>(accP1, cs1, x1, gw, cw, out, P);
    }
}

// Round 4
// 142.513 us; speedup vs baseline: 1.7626x; 1.7578x over previous
//
#include <hip/hip_runtime.h>
#include <hip/hip_fp16.h>

// Problem constants (B=4, C=128, H=W=64 -> HW=4096)
#define BATCH 4
#define CCH   128
#define HWSZ  4096

typedef _Float16 half8 __attribute__((ext_vector_type(8)));
typedef short short8 __attribute__((ext_vector_type(8)));
typedef float floatx4 __attribute__((ext_vector_type(4)));
typedef unsigned short ushort4v __attribute__((ext_vector_type(4)));

__device__ __forceinline__ unsigned short f2bf(float f) {
    union { float f; unsigned u; } v; v.f = f;
    return (unsigned short)((v.u + 0x7fffu + ((v.u >> 16) & 1u)) >> 16);
}

// prep: x fp32 [B][C][HW] -> xt fp16 [B][HW][C] (transposed), xf bf16 [B][C][HW]
__global__ __launch_bounds__(256) void prep_kernel(
    const float* __restrict__ x1, const float* __restrict__ x2,
    _Float16* __restrict__ x1t, _Float16* __restrict__ x2t,
    unsigned short* __restrict__ x1f, unsigned short* __restrict__ x2f)
{
    __shared__ float lds[32][33];
    int idx = blockIdx.x;            // 0..4095
    int which = idx >> 11;           // 0: x1, 1: x2
    int r = idx & 2047;
    int cb  = r & 3;                 // C/32  = 4
    int hwb = (r >> 2) & 127;        // HW/32 = 128
    int b   = r >> 9;                // 4 batches
    const float* x = which ? x2 : x1;
    _Float16* xt = which ? x2t : x1t;
    unsigned short* xf = which ? x2f : x1f;
    int tid = threadIdx.x;
    int tc = tid >> 5, th = tid & 31;
    #pragma unroll
    for (int k = 0; k < 4; ++k) {
        int cl = tc + 8 * k;
        int c = cb * 32 + cl, hw = hwb * 32 + th;
        float v = x[((size_t)b * CCH + c) * HWSZ + hw];
        lds[cl][th] = v;
        xf[((size_t)b * CCH + c) * HWSZ + hw] = f2bf(v);
    }
    __syncthreads();
    #pragma unroll
    for (int k = 0; k < 4; ++k) {
        int hl = tc + 8 * k;
        xt[((size_t)b * HWSZ + hwb * 32 + hl) * CCH + cb * 32 + th] =
            (_Float16)lds[th][hl];
    }
}

// raw barrier: LDS drain + barrier, no vmcnt drain; sched fences keep the
// staging loads pinned on their issue side.
#define FBAR() do { __builtin_amdgcn_sched_barrier(0); \
    asm volatile("s_waitcnt lgkmcnt(0)" ::: "memory"); \
    __builtin_amdgcn_s_barrier(); \
    __builtin_amdgcn_sched_barrier(0); } while (0)

// Fused partial pass, col-tile = 128, 16 waves, LDS-staged loop streams.
// For col-slice `slice` (128 cols) and loop-part `part` (2048 rows):
//   A[row,col] = sum_c loopT[row][c]*blockT[col][c]   (fp16 MFMA, K=128)
//   E = exp(A) (bf16 -> swizzled LDS)
//   accP[c][col] += sum_row loopF[c][row]*E[row][col] (bf16 MFMA)
//   colsum[col]  += sum_row E
// Per chunk (64 rows): stage af (xt rows, 16KB) + pa (xf cols, 16KB) into
// LDS via reg-staging with swizzled LDS writes (linear coalesced global
// reads). Single-buffered AF/PA/E with 2 barriers/chunk:
//   issue loads(t+1); gram reads AF(t); E-write; B1; PV reads PA(t)+E;
//   AF<-t+1 (AF readers all pre-B1); B2; PA<-t+1 (PA readers all pre-B2).
__global__ __launch_bounds__(1024, 4) void fused_part(
    const _Float16* __restrict__ loopT,
    const _Float16* __restrict__ blockT,
    const unsigned short* __restrict__ loopF,
    float* __restrict__ accPo,    // [2][B][32][128 c][128 col]
    float* __restrict__ cso)      // [2][B][32][128]
{
    __shared__ unsigned short AF[8192];   // 64 rows x 128 c fp16, swizzled 16B units
    __shared__ unsigned short PA[8192];   // 128 c x 64 rows bf16, swizzled
    __shared__ unsigned short EB[8192];   // 128 cols x 64 rows bf16, swizzled

    int bid = blockIdx.x;
    int xcd = bid & 7, grp = bid >> 3;    // grp 0..31
    int b = xcd >> 1;                     // 2 XCDs per batch (L2 locality)
    int slice = (grp & 15) + 16 * (xcd & 1);   // 0..31 (128 cols each)
    int part = grp >> 4;                  // 0..1 (2048 rows each)
    int tid = threadIdx.x;
    int wave = tid >> 6, lane = tid & 63;
    int l16 = lane & 15, lg = lane >> 4;
    int nt = wave & 3, mh = wave >> 2;    // gram: row-tile nt, col-32-group mh
    int swz = l16 & 7;
    int ch0 = part * 32, ch1 = ch0 + 32;

    const _Float16* lT = loopT + (size_t)b * HWSZ * CCH;
    const _Float16* bT = blockT + (size_t)b * HWSZ * CCH;
    const unsigned short* lF = loopF + (size_t)b * CCH * HWSZ;

    // hoist gram B frags: col = slice*128 + mh*32 + tt*16 + l16, K=128
    half8 bfrag[2][4];
    #pragma unroll
    for (int tt = 0; tt < 2; ++tt)
        #pragma unroll
        for (int ks = 0; ks < 4; ++ks)
            bfrag[tt][ks] = *(const half8*)&bT[
                (size_t)(slice * 128 + mh * 32 + tt * 16 + l16) * CCH + ks * 32 + lg * 8];

    // staging addressing: thread owns one 16B unit of each tile.
    // AF: unit u: row=u>>4 (64), s=u&15 (16 x 16B per 256B row). global linear,
    //     LDS unit = row*16 + (s ^ (row&7))  -> conflict-free b128 frag reads.
    int arow = tid >> 4, as_ = tid & 15;
    const _Float16* afsrc = lT + (size_t)arow * CCH + as_ * 8;
    int afw = (arow * 16 + (as_ ^ (arow & 7))) * 8;      // ushort index
    // PA: unit u: c=u>>3 (128), s=u&7 (8 x 16B per 128B row-chunk)
    int pc = tid >> 3, ps = tid & 7;
    const unsigned short* pasrc = lF + (size_t)pc * HWSZ + ps * 8;
    int paw = (pc * 8 + (ps ^ (pc & 7))) * 8;            // ushort index

    float csum0 = 0.f, csum1 = 0.f;
    floatx4 accP[2][2];
    #pragma unroll
    for (int ci = 0; ci < 2; ++ci)
        #pragma unroll
        for (int cj = 0; cj < 2; ++cj) accP[ci][cj] = (floatx4){0.f, 0.f, 0.f, 0.f};

    // E-tile addresses (loop-invariant)
    int wo0 = (mh * 32 + l16) * 64 + (((nt * 2 + (lg >> 1)) ^ swz) << 3) + ((lg & 1) << 2);
    int wo1 = wo0 + 16 * 64;

    // prologue: stage chunk ch0
    {
        floatx4 ga = *(const floatx4*)(afsrc + (size_t)ch0 * 64 * CCH);
        floatx4 gp = *(const floatx4*)(pasrc + ch0 * 64);
        *(floatx4*)&AF[afw] = ga;
        *(floatx4*)&PA[paw] = gp;
    }
    __syncthreads();

    for (int t = ch0; t < ch1; ++t) {
        int t1 = (t + 1 < ch1) ? t + 1 : t;
        // issue next-chunk staging loads (ride over both barriers)
        floatx4 ga = *(const floatx4*)(afsrc + (size_t)t1 * 64 * CCH);
        floatx4 gp = *(const floatx4*)(pasrc + t1 * 64);
        // ---- gram: rows nt*16.., cols mh*32 + {0,16} + l16, K=128 (fp16)
        half8 afr[4];
        #pragma unroll
        for (int ks = 0; ks < 4; ++ks)
            afr[ks] = *(const half8*)&AF[((nt * 16 + l16) * 16 + ((ks * 4 + lg) ^ swz)) * 8];
        floatx4 accA0 = {0.f, 0.f, 0.f, 0.f}, accA1 = {0.f, 0.f, 0.f, 0.f};
        #pragma unroll
        for (int ks = 0; ks < 4; ++ks) {
            accA0 = __builtin_amdgcn_mfma_f32_16x16x32_f16(afr[ks], bfrag[0][ks], accA0, 0, 0, 0);
            accA1 = __builtin_amdgcn_mfma_f32_16x16x32_f16(afr[ks], bfrag[1][ks], accA1, 0, 0, 0);
        }
        // ---- exp (no max-sub: |A| << 88) + bf16 pack + colsum partials
        ushort4v e0, e1;
        #pragma unroll
        for (int rr = 0; rr < 4; ++rr) {
            float v0 = __expf(accA0[rr]); csum0 += v0; e0[rr] = f2bf(v0);
            float v1 = __expf(accA1[rr]); csum1 += v1; e1[rr] = f2bf(v1);
        }
        *(ushort4v*)&EB[wo0] = e0;
        *(ushort4v*)&EB[wo1] = e1;
        FBAR();   // B1: E visible; all AF reads of tile t complete block-wide
        // ---- PV: accP[c-tiles nt*2+ci][col-tiles mh*2+cj], k = 64 rows (bf16)
        #pragma unroll
        for (int kf = 0; kf < 2; ++kf) {
            short8 paf[2], ebf[2];
            #pragma unroll
            for (int ci = 0; ci < 2; ++ci) {
                int c = (nt * 2 + ci) * 16 + l16;
                paf[ci] = *(const short8*)&PA[(c * 8 + ((kf * 4 + lg) ^ swz)) * 8];
            }
            #pragma unroll
            for (int cj = 0; cj < 2; ++cj) {
                int ecol = (mh * 2 + cj) * 16 + l16;
                ebf[cj] = *(const short8*)&EB[ecol * 64 + (((kf * 4 + lg) ^ swz) << 3)];
            }
            #pragma unroll
            for (int ci = 0; ci < 2; ++ci)
                #pragma unroll
                for (int cj = 0; cj < 2; ++cj)
                    accP[ci][cj] = __builtin_amdgcn_mfma_f32_16x16x32_bf16(
                        paf[ci], ebf[cj], accP[ci][cj], 0, 0, 0);
        }
        // ---- stage writes: AF (readers finished at B1), then barrier, then PA
        *(floatx4*)&AF[afw] = ga;
        FBAR();   // B2: PV reads of tile t complete; AF(t+1) visible
        *(floatx4*)&PA[paw] = gp;   // visible at next B1
    }
    __syncthreads();   // final PA write drained before aliasing

    // ---- colsum: deterministic cross-wave reduce (alias scratch onto PA)
    float* cspart = (float*)PA;   // [4][128]
    float v = csum0;
    v += __shfl_xor(v, 16, 64); v += __shfl_xor(v, 32, 64);
    float w = csum1;
    w += __shfl_xor(w, 16, 64); w += __shfl_xor(w, 32, 64);
    if (lane < 16) {
        cspart[nt * 128 + mh * 32 + lane] = v;
        cspart[nt * 128 + mh * 32 + 16 + lane] = w;
    }
    __syncthreads();
    size_t sbase = ((size_t)part * BATCH + b) * 32 + slice;
    if (tid < 128)
        cso[sbase * 128 + tid] = cspart[tid] + cspart[128 + tid] +
                                 cspart[256 + tid] + cspart[384 + tid];

    // ---- store partial accP: c = (nt*2+ci)*16 + lg*4 + rr, col = (mh*2+cj)*16 + l16
    float* po = accPo + sbase * (128 * 128);
    #pragma unroll
    for (int ci = 0; ci < 2; ++ci)
        #pragma unroll
        for (int cj = 0; cj < 2; ++cj)
            #pragma unroll
            for (int rr = 0; rr < 4; ++rr)
                po[(size_t)((nt * 2 + ci) * 16 + lg * 4 + rr) * 128 +
                   (mh * 2 + cj) * 16 + l16] = accP[ci][cj][rr];
}

// combine 2 partials + epilogue: att = accP/colsum;
// out[col] (+)= cw * sum_c gw[c]*sigmoid(att[c][col])*xe[c][col]
template<int ACCUM>
__global__ __launch_bounds__(256) void combine_kernel(
    const float* __restrict__ accPp, const float* __restrict__ csp,
    const float* __restrict__ xe, const float* __restrict__ gw,
    const float* __restrict__ cwp, float* __restrict__ out)
{
    __shared__ float red[256];
    __shared__ float gws[CCH];
    int b = blockIdx.x >> 5, slice = blockIdx.x & 31;
    int tid = threadIdx.x;
    if (tid < CCH) gws[tid] = gw[tid];
    __syncthreads();
    int col = tid & 127, half = tid >> 7;
    size_t s0 = ((size_t)b) * 32 + slice;
    size_t s1 = ((size_t)BATCH + b) * 32 + slice;
    float cs = csp[s0 * 128 + col] + csp[s1 * 128 + col];
    float inv = 1.f / cs;
    float acc = 0.f;
    for (int ci = 0; ci < 64; ++ci) {
        int c = half * 64 + ci;
        float s = accPp[(s0 * 128 + c) * 128 + col] + accPp[(s1 * 128 + c) * 128 + col];
        float att = s * inv;
        float mask = 1.f / (1.f + __expf(-att));
        acc += gws[c] * mask * xe[((size_t)b * CCH + c) * HWSZ + slice * 128 + col];
    }
    red[tid] = acc;
    __syncthreads();
    if (tid < 128) {
        float vv = cwp[0] * (red[tid] + red[tid + 128]);
        size_t o = (size_t)b * HWSZ + slice * 128 + tid;
        if (ACCUM) out[o] += vv; else out[o] = vv;
    }
}

extern "C" void kernel_launch(void* const* d_in, const int* in_sizes, int n_in,
                              void* d_out, int out_size, void* d_ws, size_t ws_size,
                              hipStream_t stream) {
    const float* x1 = (const float*)d_in[0];
    const float* x2 = (const float*)d_in[1];
    const float* gw = (const float*)d_in[2];
    const float* cw = (const float*)d_in[3];
    float* out = (float*)d_out;

    char* ws = (char*)d_ws;
    size_t elems = (size_t)BATCH * CCH * HWSZ;  // 2M
    _Float16* x1t = (_Float16*)ws;
    _Float16* x2t = (_Float16*)(ws + elems * 2);
    unsigned short* x1f = (unsigned short*)(ws + elems * 4);
    unsigned short* x2f = (unsigned short*)(ws + elems * 6);
    char* pbase = ws + elems * 8;               // 16 MB used by prep arrays

    // partials per pass: accP 2*B*32*128*128*4 = 16.78MB + cs 128KB
    size_t accPbytes = (size_t)2 * BATCH * 32 * 128 * 128 * 4;
    size_t csbytes   = (size_t)2 * BATCH * 32 * 128 * 4;
    size_t region = accPbytes + csbytes;
    size_t avail = (ws_size > elems * 8) ? ws_size - elems * 8 : 0;
    bool dual = (avail >= 2 * region);

    float* accP1 = (float*)pbase;
    float* cs1   = (float*)(pbase + accPbytes);
    float* accP2 = dual ? (float*)(pbase + region) : accP1;
    float* cs2   = dual ? (float*)(pbase + region + accPbytes) : cs1;

    prep_kernel<<<4096, 256, 0, stream>>>(x1, x2, x1t, x2t, x1f, x2f);

    if (dual) {
        // pass1 (out2 over m): loopT=x1t, blockT=x2t, loopF=x1f, xe=x2
        fused_part<<<256, 1024, 0, stream>>>(x1t, x2t, x1f, accP1, cs1);
        // pass2 (out1 over n): loopT=x2t, blockT=x1t, loopF=x2f, xe=x1
        fused_part<<<256, 1024, 0, stream>>>(x2t, x1t, x2f, accP2, cs2);
        combine_kernel<0><<<BATCH * 32, 256, 0, stream>>>(accP1, cs1, x2, gw, cw, out);
        combine_kernel<1><<<BATCH * 32, 256, 0, stream>>>(accP2, cs2, x1, gw, cw, out);
    } else {
        fused_part<<<256, 1024, 0, stream>>>(x1t, x2t, x1f, accP1, cs1);
        combine_kernel<0><<<BATCH * 32, 256, 0, stream>>>(accP1, cs1, x2, gw, cw, out);
        fused_part<<<256, 1024, 0, stream>>>(x2t, x1t, x2f, accP1, cs1);
        combine_kernel<1><<<BATCH * 32, 256, 0, stream>>>(accP1, cs1, x1, gw, cw, out);
    }
}